// Round 1
// baseline (348.550 us; speedup 1.0000x reference)
//
#include <hip/hip_runtime.h>
#include <hip/hip_bf16.h>

// Problem constants: B=2, T=2048, C=1024, H=16, D=64
#define Bq 2
#define Tq 2048
#define Cq 1024
#define Hq 16
#define Dq 64
#define Mq (Bq * Tq)  // 4096 rows

typedef __bf16 bf16x8 __attribute__((ext_vector_type(8)));
typedef float f32x4 __attribute__((ext_vector_type(4)));

static __device__ __forceinline__ unsigned short f2bf(float f) {
  union { float f; unsigned u; } v; v.f = f;
  return (unsigned short)((v.u + 0x7fffu + ((v.u >> 16) & 1u)) >> 16);
}

static __device__ __forceinline__ f32x4 mfma16(bf16x8 a, bf16x8 b, f32x4 c) {
  return __builtin_amdgcn_mfma_f32_16x16x32_bf16(a, b, c, 0, 0, 0);
}

// ---------------------------------------------------------------------------
// Kernel 1: QKV = x @ W_qkv + b_qkv, scatter to Q/K/V [B,H,T,D] bf16.
// A fp32 [4096][1024] row-major; B fp32 [1024][3072] row-major.
// Tile 128x128, BK=32, 4 waves (2x2), each wave 64x64 = 4x4 mfma frags.
// ---------------------------------------------------------------------------
__global__ __launch_bounds__(256) void qkv_gemm(
    const float* __restrict__ A, const float* __restrict__ Bm,
    const float* __restrict__ bias,
    unsigned short* __restrict__ qw, unsigned short* __restrict__ kw,
    unsigned short* __restrict__ vw) {
  const int K = 1024, N = 3072;
  __shared__ unsigned short As[128][40];  // [m][k], pad 40 for bank spread
  __shared__ unsigned short Bs[128][40];  // [n][k] (transposed store)
  const int m0 = blockIdx.x * 128, n0 = blockIdx.y * 128;
  const int t = threadIdx.x;
  const int lane = t & 63, w = t >> 6;
  const int wm = (w >> 1) * 64, wn = (w & 1) * 64;
  const int l15 = lane & 15, l4 = lane >> 4;
  f32x4 acc[4][4] = {};

  const int arow = t >> 1, ak0 = (t & 1) * 16;   // A: 2 threads/row, 16 k each
  const int bn = t & 127, bk0 = (t >> 7) * 16;   // B: 1 col/thread, 16 k each

  for (int kk = 0; kk < K; kk += 32) {
    __syncthreads();
    // stage A (fp32 -> bf16)
    const float* ap = A + (size_t)(m0 + arow) * K + kk + ak0;
#pragma unroll
    for (int i = 0; i < 4; i++) {
      float4 v = *(const float4*)(ap + 4 * i);
      ushort4 s;
      s.x = f2bf(v.x); s.y = f2bf(v.y); s.z = f2bf(v.z); s.w = f2bf(v.w);
      *(ushort4*)&As[arow][ak0 + 4 * i] = s;
    }
    // stage B transposed: thread owns one n-column, 16 consecutive k
    const float* bp = Bm + (size_t)(kk + bk0) * N + n0 + bn;
#pragma unroll
    for (int c = 0; c < 4; c++) {
      ushort4 s;
      s.x = f2bf(bp[(size_t)(4 * c + 0) * N]);
      s.y = f2bf(bp[(size_t)(4 * c + 1) * N]);
      s.z = f2bf(bp[(size_t)(4 * c + 2) * N]);
      s.w = f2bf(bp[(size_t)(4 * c + 3) * N]);
      *(ushort4*)&Bs[bn][bk0 + 4 * c] = s;
    }
    __syncthreads();
    bf16x8 af[4], bfr[4];
#pragma unroll
    for (int i = 0; i < 4; i++) {
      af[i] = *(const bf16x8*)&As[wm + i * 16 + l15][l4 * 8];
      bfr[i] = *(const bf16x8*)&Bs[wn + i * 16 + l15][l4 * 8];
    }
#pragma unroll
    for (int mi = 0; mi < 4; mi++)
#pragma unroll
      for (int ni = 0; ni < 4; ni++)
        acc[mi][ni] = mfma16(af[mi], bfr[ni], acc[mi][ni]);
  }
  // epilogue: C frag layout row=(l>>4)*4+r, col=l&15; scatter into [B,H,T,D]
#pragma unroll
  for (int mi = 0; mi < 4; mi++) {
#pragma unroll
    for (int ni = 0; ni < 4; ni++) {
#pragma unroll
      for (int r = 0; r < 4; r++) {
        int row = m0 + wm + mi * 16 + l4 * 4 + r;
        int col = n0 + wn + ni * 16 + l15;
        float val = acc[mi][ni][r] + bias[col];
        int which = col >> 10, c = col & 1023;
        int h = c >> 6, d = c & 63;
        int b = row >> 11, tt = row & 2047;
        unsigned short* dst = (which == 0) ? qw : ((which == 1) ? kw : vw);
        dst[(size_t)((b * Hq + h) * Tq + tt) * Dq + d] = f2bf(val);
      }
    }
  }
}

// ---------------------------------------------------------------------------
// Kernel 2: causal flash attention. Block = 64 q-rows of one (b,h).
// 4 waves; wave w owns q-rows [w*16, w*16+16). KV tiles of 64.
// S^... = Q K^T via mfma(Q-rows, K-as-Bop); softmax in C-layout regs;
// P staged through wave-private LDS strip into A-operand layout; PV mfma.
// ---------------------------------------------------------------------------
__global__ __launch_bounds__(256) void attn(
    const unsigned short* __restrict__ qw, const unsigned short* __restrict__ kw,
    const unsigned short* __restrict__ vw, unsigned short* __restrict__ yw) {
  const int qb = blockIdx.x;  // q tile (32)
  const int bh = blockIdx.y;  // b*H+h (32)
  __shared__ unsigned short Qs[64][72];
  __shared__ unsigned short Ks[64][72];
  __shared__ unsigned short Vs[64][72];
  __shared__ unsigned short Ps[64][72];
  const int t = threadIdx.x;
  const int lane = t & 63, w = t >> 6;
  const int l15 = lane & 15, l4 = lane >> 4;
  const size_t base = (size_t)bh * Tq * Dq;
  const unsigned short* qp = qw + base;
  const unsigned short* kp = kw + base;
  const unsigned short* vp = vw + base;

  {  // stage Q tile once
    int r = t >> 2, d0 = (t & 3) * 16;
    const unsigned short* s = qp + (size_t)(qb * 64 + r) * Dq + d0;
    *(uint4*)&Qs[r][d0] = *(const uint4*)s;
    *(uint4*)&Qs[r][d0 + 8] = *(const uint4*)(s + 8);
  }
  __syncthreads();
  bf16x8 qf0 = *(const bf16x8*)&Qs[w * 16 + l15][l4 * 8];
  bf16x8 qf1 = *(const bf16x8*)&Qs[w * 16 + l15][32 + l4 * 8];

  float m[4], lsum[4];
  f32x4 accO[4] = {};
#pragma unroll
  for (int r = 0; r < 4; r++) { m[r] = -1e30f; lsum[r] = 0.f; }

  // softmax tracked in exp2 domain: s2 = s * (1/8) * log2(e)
  const float kscale = 0.125f * 1.44269504088896340736f;

  for (int kv = 0; kv <= qb; kv++) {
    __syncthreads();  // protect LDS reuse from previous iteration's readers
    {  // stage K and V tiles (coalesced, b128 LDS writes)
      int r = t >> 2, d0 = (t & 3) * 16;
      const unsigned short* ks = kp + (size_t)(kv * 64 + r) * Dq + d0;
      *(uint4*)&Ks[r][d0] = *(const uint4*)ks;
      *(uint4*)&Ks[r][d0 + 8] = *(const uint4*)(ks + 8);
      const unsigned short* vs = vp + (size_t)(kv * 64 + r) * Dq + d0;
      *(uint4*)&Vs[r][d0] = *(const uint4*)vs;
      *(uint4*)&Vs[r][d0 + 8] = *(const uint4*)(vs + 8);
    }
    __syncthreads();

    // S strip [16 q][64 k] = 4 col-tiles, each K-chained over d=64 (2 mfma)
    f32x4 s[4];
#pragma unroll
    for (int ct = 0; ct < 4; ct++) {
      bf16x8 kf0 = *(const bf16x8*)&Ks[ct * 16 + l15][l4 * 8];
      bf16x8 kf1 = *(const bf16x8*)&Ks[ct * 16 + l15][32 + l4 * 8];
      f32x4 z = {};
      z = mfma16(qf0, kf0, z);
      z = mfma16(qf1, kf1, z);
      s[ct] = z;
    }
    // scale (+ causal mask on diagonal tile)
    if (kv == qb) {
#pragma unroll
      for (int ct = 0; ct < 4; ct++)
#pragma unroll
        for (int r = 0; r < 4; r++) {
          int ql = w * 16 + l4 * 4 + r, kl = ct * 16 + l15;
          s[ct][r] = (kl > ql) ? -1e30f : s[ct][r] * kscale;
        }
    } else {
#pragma unroll
      for (int ct = 0; ct < 4; ct++)
#pragma unroll
        for (int r = 0; r < 4; r++) s[ct][r] *= kscale;
    }

    // row max: lane-local over 4 col-tiles, then 16-lane butterfly (k axis)
    float corr[4], psum[4];
#pragma unroll
    for (int r = 0; r < 4; r++) {
      float v = fmaxf(fmaxf(s[0][r], s[1][r]), fmaxf(s[2][r], s[3][r]));
#pragma unroll
      for (int off = 1; off < 16; off <<= 1) v = fmaxf(v, __shfl_xor(v, off));
      float mn = fmaxf(m[r], v);
      corr[r] = exp2f(m[r] - mn);
      m[r] = mn;
      psum[r] = 0.f;
    }
    // P = exp2(s - m); write to wave-private LDS strip in A-operand layout
#pragma unroll
    for (int ct = 0; ct < 4; ct++)
#pragma unroll
      for (int r = 0; r < 4; r++) {
        float p = exp2f(s[ct][r] - m[r]);
        psum[r] += p;
        Ps[w * 16 + l4 * 4 + r][ct * 16 + l15] = f2bf(p);
      }
#pragma unroll
    for (int r = 0; r < 4; r++) {
      float v = psum[r];
#pragma unroll
      for (int off = 1; off < 16; off <<= 1) v += __shfl_xor(v, off);
      lsum[r] = lsum[r] * corr[r] + v;
    }
#pragma unroll
    for (int dt = 0; dt < 4; dt++)
#pragma unroll
      for (int r = 0; r < 4; r++) accO[dt][r] *= corr[r];

    // PV: A = P strip (wave-private, no barrier needed: in-wave LDS ordering)
    bf16x8 pf0 = *(const bf16x8*)&Ps[w * 16 + l15][l4 * 8];
    bf16x8 pf1 = *(const bf16x8*)&Ps[w * 16 + l15][32 + l4 * 8];
#pragma unroll
    for (int dt = 0; dt < 4; dt++) {
      bf16x8 vf0, vf1;
#pragma unroll
      for (int i = 0; i < 8; i++) {  // column reads of Vs (B-operand layout)
        vf0[i] = *(const __bf16*)&Vs[l4 * 8 + i][dt * 16 + l15];
        vf1[i] = *(const __bf16*)&Vs[32 + l4 * 8 + i][dt * 16 + l15];
      }
      accO[dt] = mfma16(pf0, vf0, accO[dt]);
      accO[dt] = mfma16(pf1, vf1, accO[dt]);
    }
  }

  // epilogue: normalize and write y [B,T,H*D] bf16
  const int b = bh >> 4, h = bh & 15;
#pragma unroll
  for (int r = 0; r < 4; r++) {
    float inv = 1.0f / lsum[r];
    int tt = qb * 64 + w * 16 + l4 * 4 + r;
    size_t rowbase = ((size_t)(b * Tq + tt)) * Cq + h * 64;
#pragma unroll
    for (int dt = 0; dt < 4; dt++)
      yw[rowbase + dt * 16 + l15] = f2bf(accO[dt][r] * inv);
  }
}

// ---------------------------------------------------------------------------
// Kernel 3: out = y @ W_proj + b_proj. A bf16 [4096][1024], B fp32 [1024][1024],
// out fp32. Same tile structure as kernel 1.
// ---------------------------------------------------------------------------
__global__ __launch_bounds__(256) void proj_gemm(
    const unsigned short* __restrict__ Aw, const float* __restrict__ Bm,
    const float* __restrict__ bias, float* __restrict__ out) {
  const int K = 1024, N = 1024;
  __shared__ unsigned short As[128][40];
  __shared__ unsigned short Bs[128][40];
  const int m0 = blockIdx.x * 128, n0 = blockIdx.y * 128;
  const int t = threadIdx.x;
  const int lane = t & 63, w = t >> 6;
  const int wm = (w >> 1) * 64, wn = (w & 1) * 64;
  const int l15 = lane & 15, l4 = lane >> 4;
  f32x4 acc[4][4] = {};

  const int arow = t >> 1, ak0 = (t & 1) * 16;
  const int bn = t & 127, bk0 = (t >> 7) * 16;

  for (int kk = 0; kk < K; kk += 32) {
    __syncthreads();
    const unsigned short* ap = Aw + (size_t)(m0 + arow) * K + kk + ak0;
    *(uint4*)&As[arow][ak0] = *(const uint4*)ap;
    *(uint4*)&As[arow][ak0 + 8] = *(const uint4*)(ap + 8);
    const float* bp = Bm + (size_t)(kk + bk0) * N + n0 + bn;
#pragma unroll
    for (int c = 0; c < 4; c++) {
      ushort4 s;
      s.x = f2bf(bp[(size_t)(4 * c + 0) * N]);
      s.y = f2bf(bp[(size_t)(4 * c + 1) * N]);
      s.z = f2bf(bp[(size_t)(4 * c + 2) * N]);
      s.w = f2bf(bp[(size_t)(4 * c + 3) * N]);
      *(ushort4*)&Bs[bn][bk0 + 4 * c] = s;
    }
    __syncthreads();
    bf16x8 af[4], bfr[4];
#pragma unroll
    for (int i = 0; i < 4; i++) {
      af[i] = *(const bf16x8*)&As[wm + i * 16 + l15][l4 * 8];
      bfr[i] = *(const bf16x8*)&Bs[wn + i * 16 + l15][l4 * 8];
    }
#pragma unroll
    for (int mi = 0; mi < 4; mi++)
#pragma unroll
      for (int ni = 0; ni < 4; ni++)
        acc[mi][ni] = mfma16(af[mi], bfr[ni], acc[mi][ni]);
  }
#pragma unroll
  for (int mi = 0; mi < 4; mi++) {
#pragma unroll
    for (int ni = 0; ni < 4; ni++) {
#pragma unroll
      for (int r = 0; r < 4; r++) {
        int row = m0 + wm + mi * 16 + l4 * 4 + r;
        int col = n0 + wn + ni * 16 + l15;
        out[(size_t)row * N + col] = acc[mi][ni][r] + bias[col];
      }
    }
  }
}

// ---------------------------------------------------------------------------
// Workspace layout (bf16 elements): Q | K | V : [B,H,T,D] each (8 MB), then
// y [B,T,C] (8 MB). Total 32 MB.
// ---------------------------------------------------------------------------
extern "C" void kernel_launch(void* const* d_in, const int* in_sizes, int n_in,
                              void* d_out, int out_size, void* d_ws, size_t ws_size,
                              hipStream_t stream) {
  const float* x = (const float*)d_in[0];
  const float* W_qkv = (const float*)d_in[1];
  const float* b_qkv = (const float*)d_in[2];
  const float* W_proj = (const float*)d_in[3];
  const float* b_proj = (const float*)d_in[4];
  float* out = (float*)d_out;

  const size_t qkv_elems = (size_t)Bq * Hq * Tq * Dq;  // 4M
  unsigned short* qw = (unsigned short*)d_ws;
  unsigned short* kw = qw + qkv_elems;
  unsigned short* vw = kw + qkv_elems;
  unsigned short* yw = vw + qkv_elems;

  qkv_gemm<<<dim3(Mq / 128, 3 * Cq / 128), 256, 0, stream>>>(x, W_qkv, b_qkv, qw, kw, vw);
  attn<<<dim3(Tq / 64, Bq * Hq), 256, 0, stream>>>(qw, kw, vw, yw);
  proj_gemm<<<dim3(Mq / 128, Cq / 128), 256, 0, stream>>>(yw, W_proj, b_proj, out);
}

// Round 2
// 294.866 us; speedup vs baseline: 1.1821x; 1.1821x over previous
//
#include <hip/hip_runtime.h>
#include <hip/hip_bf16.h>

// Problem constants: B=2, T=2048, C=1024, H=16, D=64
#define Bq 2
#define Tq 2048
#define Cq 1024
#define Hq 16
#define Dq 64
#define Mq (Bq * Tq)  // 4096 rows

typedef __bf16 bf16x8 __attribute__((ext_vector_type(8)));
typedef float f32x4 __attribute__((ext_vector_type(4)));
typedef unsigned short u16;

static __device__ __forceinline__ u16 f2bf(float f) {
  union { float f; unsigned u; } v; v.f = f;
  return (u16)((v.u + 0x7fffu + ((v.u >> 16) & 1u)) >> 16);
}

static __device__ __forceinline__ f32x4 mfma16(bf16x8 a, bf16x8 b, f32x4 c) {
  return __builtin_amdgcn_mfma_f32_16x16x32_bf16(a, b, c, 0, 0, 0);
}

// async global->LDS, 16B per lane. LDS dest = wave-uniform base + lane*16.
#define GLD16(g, l)                                                   \
  __builtin_amdgcn_global_load_lds(                                   \
      (const __attribute__((address_space(1))) unsigned int*)(g),     \
      (__attribute__((address_space(3))) unsigned int*)(l), 16, 0, 0)

// ---------------------------------------------------------------------------
// Pre-pass A: x fp32 -> bf16 (4M elements)
// ---------------------------------------------------------------------------
__global__ __launch_bounds__(256) void convert_x(const float* __restrict__ x,
                                                 u16* __restrict__ xb) {
  int i = (blockIdx.x * 256 + threadIdx.x) * 8;
  float4 a = *(const float4*)(x + i);
  float4 b = *(const float4*)(x + i + 4);
  u16 tmp[8];
  tmp[0] = f2bf(a.x); tmp[1] = f2bf(a.y); tmp[2] = f2bf(a.z); tmp[3] = f2bf(a.w);
  tmp[4] = f2bf(b.x); tmp[5] = f2bf(b.y); tmp[6] = f2bf(b.z); tmp[7] = f2bf(b.w);
  *(uint4*)(xb + i) = *(const uint4*)tmp;
}

// ---------------------------------------------------------------------------
// Pre-pass B: W fp32 [K][N] -> Wt bf16 [N][K] (tiled transpose via LDS)
// ---------------------------------------------------------------------------
__global__ __launch_bounds__(256) void transpose_w(const float* __restrict__ W,
                                                   u16* __restrict__ Wt,
                                                   int K, int N) {
  __shared__ __align__(16) u16 Ts[64][72];  // [n][k]
  const int k0 = blockIdx.x * 64, n0 = blockIdx.y * 64;
  const int t = threadIdx.x;
  const int r = t >> 2, c0 = (t & 3) * 16;
  const float* src = W + (size_t)(k0 + r) * N + n0 + c0;
  u16 v16[16];
#pragma unroll
  for (int i = 0; i < 4; i++) {
    float4 f = *(const float4*)(src + 4 * i);
    v16[4 * i + 0] = f2bf(f.x); v16[4 * i + 1] = f2bf(f.y);
    v16[4 * i + 2] = f2bf(f.z); v16[4 * i + 3] = f2bf(f.w);
  }
#pragma unroll
  for (int j = 0; j < 16; j++) Ts[c0 + j][r] = v16[j];
  __syncthreads();
  u16* dst = Wt + (size_t)(n0 + r) * K + k0 + c0;
  *(uint4*)dst = *(const uint4*)&Ts[r][c0];
  *(uint4*)(dst + 8) = *(const uint4*)&Ts[r][c0 + 8];
}

// ---------------------------------------------------------------------------
// Kernel 1: QKV = xb @ Wt^T + b, scatter to Q/K/V [B,H,T,D] bf16.
// m97 structure: 128x128 tile, BK=32, linear LDS, global_load_lds(16B).
// ---------------------------------------------------------------------------
__global__ __launch_bounds__(256) void qkv_gemm(
    const u16* __restrict__ A, const u16* __restrict__ Bt,
    const float* __restrict__ bias,
    u16* __restrict__ qw, u16* __restrict__ kw, u16* __restrict__ vw) {
  const int K = 1024;
  __shared__ __align__(16) u16 As[128][32];
  __shared__ __align__(16) u16 Bs[128][32];
  const int m0 = blockIdx.x * 128, n0 = blockIdx.y * 128;
  const int t = threadIdx.x, lane = t & 63, w = t >> 6;
  const int wm = (w >> 1) * 64, wn = (w & 1) * 64;
  const int l15 = lane & 15, l4 = lane >> 4;
  const int lr = lane >> 2, lc = (lane & 3) * 8;
  f32x4 acc[4][4] = {};
  const u16* ga = A + (size_t)(m0 + w * 16 + lr) * K + lc;
  const u16* gb = Bt + (size_t)(n0 + w * 16 + lr) * K + lc;

  for (int kk = 0; kk < K; kk += 32) {
    __syncthreads();
    GLD16(ga + kk, &As[w * 16][0]);
    GLD16(ga + (size_t)64 * K + kk, &As[64 + w * 16][0]);
    GLD16(gb + kk, &Bs[w * 16][0]);
    GLD16(gb + (size_t)64 * K + kk, &Bs[64 + w * 16][0]);
    __syncthreads();
    bf16x8 af[4], bfr[4];
#pragma unroll
    for (int i = 0; i < 4; i++) {
      af[i] = *(const bf16x8*)&As[wm + i * 16 + l15][l4 * 8];
      bfr[i] = *(const bf16x8*)&Bs[wn + i * 16 + l15][l4 * 8];
    }
#pragma unroll
    for (int mi = 0; mi < 4; mi++)
#pragma unroll
      for (int ni = 0; ni < 4; ni++)
        acc[mi][ni] = mfma16(af[mi], bfr[ni], acc[mi][ni]);
  }
  // C frag: row=(l>>4)*4+r, col=l&15; scatter into [B,H,T,D]
#pragma unroll
  for (int mi = 0; mi < 4; mi++) {
#pragma unroll
    for (int ni = 0; ni < 4; ni++) {
#pragma unroll
      for (int r = 0; r < 4; r++) {
        int row = m0 + wm + mi * 16 + l4 * 4 + r;
        int col = n0 + wn + ni * 16 + l15;
        float val = acc[mi][ni][r] + bias[col];
        int which = col >> 10, c = col & 1023;
        int h = c >> 6, d = c & 63;
        int b = row >> 11, tt = row & 2047;
        u16* dst = (which == 0) ? qw : ((which == 1) ? kw : vw);
        dst[(size_t)((b * Hq + h) * Tq + tt) * Dq + d] = f2bf(val);
      }
    }
  }
}

// ---------------------------------------------------------------------------
// Kernel 2: causal flash attention. Block = 64 q-rows of one (b,h), 4 waves.
// V stored TRANSPOSED in LDS so PV B-frags are contiguous ds_read_b128.
// Ps aliases Qs (both wave-private 16-row strips). Heavy blocks launch first.
// ---------------------------------------------------------------------------
__global__ __launch_bounds__(256) void attn(
    const u16* __restrict__ qw, const u16* __restrict__ kw,
    const u16* __restrict__ vw, u16* __restrict__ yw) {
  const int qb = gridDim.x - 1 - blockIdx.x;  // heavy-first
  const int bh = blockIdx.y;
  __shared__ __align__(16) u16 QPs[64][72];  // Q tile, then reused as P
  __shared__ __align__(16) u16 Ks[64][72];   // K natural [k][d]
  __shared__ __align__(16) u16 Vt[64][72];   // V transposed [d][k]
  const int t = threadIdx.x;
  const int lane = t & 63, w = t >> 6;
  const int l15 = lane & 15, l4 = lane >> 4;
  const size_t base = (size_t)bh * Tq * Dq;
  const u16* qp = qw + base;
  const u16* kp = kw + base;
  const u16* vp = vw + base;
  const int rr = t >> 2, q4 = t & 3, d0 = q4 * 16;

  {  // stage Q tile (wave-private rows)
    const u16* s = qp + (size_t)(qb * 64 + rr) * Dq + d0;
    *(uint4*)&QPs[rr][d0] = *(const uint4*)s;
    *(uint4*)&QPs[rr][d0 + 8] = *(const uint4*)(s + 8);
  }
  __syncthreads();
  bf16x8 qf0 = *(const bf16x8*)&QPs[w * 16 + l15][l4 * 8];
  bf16x8 qf1 = *(const bf16x8*)&QPs[w * 16 + l15][32 + l4 * 8];

  float m[4], lsum[4];
  f32x4 accO[4] = {};
#pragma unroll
  for (int r = 0; r < 4; r++) { m[r] = -1e30f; lsum[r] = 0.f; }

  const float kscale = 0.125f * 1.44269504088896340736f;  // exp2 domain

  for (int kv = 0; kv <= qb; kv++) {
    __syncthreads();  // prev iteration's LDS readers done
    {  // stage K natural (b128), V transposed (scalar writes)
      const u16* ks = kp + (size_t)(kv * 64 + rr) * Dq + d0;
      *(uint4*)&Ks[rr][d0] = *(const uint4*)ks;
      *(uint4*)&Ks[rr][d0 + 8] = *(const uint4*)(ks + 8);
      const u16* vs = vp + (size_t)(kv * 64 + rr) * Dq + d0;
      u16 v16[16];
      *(uint4*)&v16[0] = *(const uint4*)vs;
      *(uint4*)&v16[8] = *(const uint4*)(vs + 8);
#pragma unroll
      for (int j = 0; j < 16; j++) Vt[d0 + j][rr] = v16[j];
    }
    __syncthreads();

    // S strip [16 q][64 k]
    f32x4 s[4];
#pragma unroll
    for (int ct = 0; ct < 4; ct++) {
      bf16x8 kf0 = *(const bf16x8*)&Ks[ct * 16 + l15][l4 * 8];
      bf16x8 kf1 = *(const bf16x8*)&Ks[ct * 16 + l15][32 + l4 * 8];
      f32x4 z = {};
      z = mfma16(qf0, kf0, z);
      z = mfma16(qf1, kf1, z);
      s[ct] = z;
    }
    if (kv == qb) {
#pragma unroll
      for (int ct = 0; ct < 4; ct++)
#pragma unroll
        for (int r = 0; r < 4; r++) {
          int ql = w * 16 + l4 * 4 + r, kl = ct * 16 + l15;
          s[ct][r] = (kl > ql) ? -1e30f : s[ct][r] * kscale;
        }
    } else {
#pragma unroll
      for (int ct = 0; ct < 4; ct++)
#pragma unroll
        for (int r = 0; r < 4; r++) s[ct][r] *= kscale;
    }

    float corr[4], psum[4];
#pragma unroll
    for (int r = 0; r < 4; r++) {
      float v = fmaxf(fmaxf(s[0][r], s[1][r]), fmaxf(s[2][r], s[3][r]));
#pragma unroll
      for (int off = 1; off < 16; off <<= 1) v = fmaxf(v, __shfl_xor(v, off));
      float mn = fmaxf(m[r], v);
      corr[r] = exp2f(m[r] - mn);
      m[r] = mn;
      psum[r] = 0.f;
    }
    // P = exp2(s - m) -> wave-private LDS strip (aliases Q strip)
#pragma unroll
    for (int ct = 0; ct < 4; ct++)
#pragma unroll
      for (int r = 0; r < 4; r++) {
        float p = exp2f(s[ct][r] - m[r]);
        psum[r] += p;
        QPs[w * 16 + l4 * 4 + r][ct * 16 + l15] = f2bf(p);
      }
#pragma unroll
    for (int r = 0; r < 4; r++) {
      float v = psum[r];
#pragma unroll
      for (int off = 1; off < 16; off <<= 1) v += __shfl_xor(v, off);
      lsum[r] = lsum[r] * corr[r] + v;
    }
#pragma unroll
    for (int dt = 0; dt < 4; dt++)
#pragma unroll
      for (int r = 0; r < 4; r++) accO[dt][r] *= corr[r];

    // PV: A = P (wave-private, in-wave ordering), B = Vt rows (b128 reads)
    bf16x8 pf0 = *(const bf16x8*)&QPs[w * 16 + l15][l4 * 8];
    bf16x8 pf1 = *(const bf16x8*)&QPs[w * 16 + l15][32 + l4 * 8];
#pragma unroll
    for (int dt = 0; dt < 4; dt++) {
      bf16x8 vf0 = *(const bf16x8*)&Vt[dt * 16 + l15][l4 * 8];
      bf16x8 vf1 = *(const bf16x8*)&Vt[dt * 16 + l15][32 + l4 * 8];
      accO[dt] = mfma16(pf0, vf0, accO[dt]);
      accO[dt] = mfma16(pf1, vf1, accO[dt]);
    }
  }

  // epilogue: normalize, write y [B,T,C] bf16
  const int b = bh >> 4, h = bh & 15;
#pragma unroll
  for (int r = 0; r < 4; r++) {
    float inv = 1.0f / lsum[r];
    int tt = qb * 64 + w * 16 + l4 * 4 + r;
    size_t rowbase = ((size_t)(b * Tq + tt)) * Cq + h * 64;
#pragma unroll
    for (int dt = 0; dt < 4; dt++)
      yw[rowbase + dt * 16 + l15] = f2bf(accO[dt][r] * inv);
  }
}

// ---------------------------------------------------------------------------
// Kernel 3: out = y @ Wt_proj^T + b_proj (fp32 out). m97 structure.
// ---------------------------------------------------------------------------
__global__ __launch_bounds__(256) void proj_gemm(
    const u16* __restrict__ A, const u16* __restrict__ Bt,
    const float* __restrict__ bias, float* __restrict__ out) {
  const int K = 1024, N = 1024;
  __shared__ __align__(16) u16 As[128][32];
  __shared__ __align__(16) u16 Bs[128][32];
  const int m0 = blockIdx.x * 128, n0 = blockIdx.y * 128;
  const int t = threadIdx.x, lane = t & 63, w = t >> 6;
  const int wm = (w >> 1) * 64, wn = (w & 1) * 64;
  const int l15 = lane & 15, l4 = lane >> 4;
  const int lr = lane >> 2, lc = (lane & 3) * 8;
  f32x4 acc[4][4] = {};
  const u16* ga = A + (size_t)(m0 + w * 16 + lr) * K + lc;
  const u16* gb = Bt + (size_t)(n0 + w * 16 + lr) * K + lc;

  for (int kk = 0; kk < K; kk += 32) {
    __syncthreads();
    GLD16(ga + kk, &As[w * 16][0]);
    GLD16(ga + (size_t)64 * K + kk, &As[64 + w * 16][0]);
    GLD16(gb + kk, &Bs[w * 16][0]);
    GLD16(gb + (size_t)64 * K + kk, &Bs[64 + w * 16][0]);
    __syncthreads();
    bf16x8 af[4], bfr[4];
#pragma unroll
    for (int i = 0; i < 4; i++) {
      af[i] = *(const bf16x8*)&As[wm + i * 16 + l15][l4 * 8];
      bfr[i] = *(const bf16x8*)&Bs[wn + i * 16 + l15][l4 * 8];
    }
#pragma unroll
    for (int mi = 0; mi < 4; mi++)
#pragma unroll
      for (int ni = 0; ni < 4; ni++)
        acc[mi][ni] = mfma16(af[mi], bfr[ni], acc[mi][ni]);
  }
#pragma unroll
  for (int mi = 0; mi < 4; mi++) {
#pragma unroll
    for (int ni = 0; ni < 4; ni++) {
#pragma unroll
      for (int r = 0; r < 4; r++) {
        int row = m0 + wm + mi * 16 + l4 * 4 + r;
        int col = n0 + wn + ni * 16 + l15;
        out[(size_t)row * N + col] = acc[mi][ni][r] + bias[col];
      }
    }
  }
}

// ---------------------------------------------------------------------------
// Workspace (bytes): qw 8M | kw 8M | vw 8M | xb/yw 8M | Wt 6M = 38 MB
// ---------------------------------------------------------------------------
extern "C" void kernel_launch(void* const* d_in, const int* in_sizes, int n_in,
                              void* d_out, int out_size, void* d_ws, size_t ws_size,
                              hipStream_t stream) {
  const float* x = (const float*)d_in[0];
  const float* W_qkv = (const float*)d_in[1];
  const float* b_qkv = (const float*)d_in[2];
  const float* W_proj = (const float*)d_in[3];
  const float* b_proj = (const float*)d_in[4];
  float* out = (float*)d_out;

  const size_t qkv_elems = (size_t)Bq * Hq * Tq * Dq;  // 4M
  u16* qw = (u16*)d_ws;
  u16* kw = qw + qkv_elems;
  u16* vw = kw + qkv_elems;
  u16* xb = vw + qkv_elems;          // reused as yw after qkv_gemm
  u16* wt = xb + (size_t)Mq * Cq;    // 3072*1024 bf16 max

  convert_x<<<dim3((Mq * Cq) / (256 * 8)), 256, 0, stream>>>(x, xb);
  transpose_w<<<dim3(Cq / 64, 3 * Cq / 64), 256, 0, stream>>>(W_qkv, wt, Cq, 3 * Cq);
  qkv_gemm<<<dim3(Mq / 128, 3 * Cq / 128), 256, 0, stream>>>(xb, wt, b_qkv, qw, kw, vw);
  transpose_w<<<dim3(Cq / 64, Cq / 64), 256, 0, stream>>>(W_proj, wt, Cq, Cq);
  u16* yw = xb;
  attn<<<dim3(Tq / 64, Bq * Hq), 256, 0, stream>>>(qw, kw, vw, yw);
  proj_gemm<<<dim3(Mq / 128, Cq / 128), 256, 0, stream>>>(yw, wt, b_proj, out);
}

// Round 3
// 249.465 us; speedup vs baseline: 1.3972x; 1.1820x over previous
//
#include <hip/hip_runtime.h>
#include <hip/hip_bf16.h>

// Problem constants: B=2, T=2048, C=1024, H=16, D=64
#define Bq 2
#define Tq 2048
#define Cq 1024
#define Hq 16
#define Dq 64
#define Mq (Bq * Tq)  // 4096 rows

typedef __bf16 bf16x8 __attribute__((ext_vector_type(8)));
typedef float f32x4 __attribute__((ext_vector_type(4)));
typedef unsigned short u16;

static __device__ __forceinline__ u16 f2bf(float f) {
  union { float f; unsigned u; } v; v.f = f;
  return (u16)((v.u + 0x7fffu + ((v.u >> 16) & 1u)) >> 16);
}

static __device__ __forceinline__ f32x4 mfma16(bf16x8 a, bf16x8 b, f32x4 c) {
  return __builtin_amdgcn_mfma_f32_16x16x32_bf16(a, b, c, 0, 0, 0);
}

// async global->LDS, 16B per lane. LDS dest = wave-uniform base + lane*16.
#define GLD16(g, l)                                                   \
  __builtin_amdgcn_global_load_lds(                                   \
      (const __attribute__((address_space(1))) unsigned int*)(g),     \
      (__attribute__((address_space(3))) unsigned int*)(l), 16, 0, 0)

// XOR granule swizzle: 8-u16 granules, granule ^= (row>>3)&7 (bank-exact for
// row stride 72 u16: makes V-transpose scalar writes conflict-free and P
// writes ~2-way; b128 reads stay uniform).
static __device__ __forceinline__ int swz(int col, int row) {
  return (col & 7) + 8 * (((col >> 3) ^ (row >> 3)) & 7);
}

// ---------------------------------------------------------------------------
// Pre-pass A: x fp32 -> bf16 (4M elements)
// ---------------------------------------------------------------------------
__global__ __launch_bounds__(256) void convert_x(const float* __restrict__ x,
                                                 u16* __restrict__ xb) {
  int i = (blockIdx.x * 256 + threadIdx.x) * 8;
  float4 a = *(const float4*)(x + i);
  float4 b = *(const float4*)(x + i + 4);
  u16 tmp[8];
  tmp[0] = f2bf(a.x); tmp[1] = f2bf(a.y); tmp[2] = f2bf(a.z); tmp[3] = f2bf(a.w);
  tmp[4] = f2bf(b.x); tmp[5] = f2bf(b.y); tmp[6] = f2bf(b.z); tmp[7] = f2bf(b.w);
  *(uint4*)(xb + i) = *(const uint4*)tmp;
}

// ---------------------------------------------------------------------------
// Pre-pass B: W fp32 [K][N] -> Wt bf16 [N][K] (tiled transpose via LDS)
// ---------------------------------------------------------------------------
__global__ __launch_bounds__(256) void transpose_w(const float* __restrict__ W,
                                                   u16* __restrict__ Wt,
                                                   int K, int N) {
  __shared__ __align__(16) u16 Ts[64][72];  // [n][k]
  const int k0 = blockIdx.x * 64, n0 = blockIdx.y * 64;
  const int t = threadIdx.x;
  const int r = t >> 2, c0 = (t & 3) * 16;
  const float* src = W + (size_t)(k0 + r) * N + n0 + c0;
  u16 v16[16];
#pragma unroll
  for (int i = 0; i < 4; i++) {
    float4 f = *(const float4*)(src + 4 * i);
    v16[4 * i + 0] = f2bf(f.x); v16[4 * i + 1] = f2bf(f.y);
    v16[4 * i + 2] = f2bf(f.z); v16[4 * i + 3] = f2bf(f.w);
  }
#pragma unroll
  for (int j = 0; j < 16; j++) Ts[c0 + j][r] = v16[j];
  __syncthreads();
  u16* dst = Wt + (size_t)(n0 + r) * K + k0 + c0;
  *(uint4*)dst = *(const uint4*)&Ts[r][c0];
  *(uint4*)(dst + 8) = *(const uint4*)&Ts[r][c0 + 8];
}

// ---------------------------------------------------------------------------
// Kernel 1: QKV = xb @ Wt^T + b, scatter to Q/K/V [B,H,T,D] bf16.
// m97 structure: 128x128 tile, BK=32, linear LDS, global_load_lds(16B).
// ---------------------------------------------------------------------------
__global__ __launch_bounds__(256) void qkv_gemm(
    const u16* __restrict__ A, const u16* __restrict__ Bt,
    const float* __restrict__ bias,
    u16* __restrict__ qw, u16* __restrict__ kw, u16* __restrict__ vw) {
  const int K = 1024;
  __shared__ __align__(16) u16 As[128][32];
  __shared__ __align__(16) u16 Bs[128][32];
  const int m0 = blockIdx.x * 128, n0 = blockIdx.y * 128;
  const int t = threadIdx.x, lane = t & 63, w = t >> 6;
  const int wm = (w >> 1) * 64, wn = (w & 1) * 64;
  const int l15 = lane & 15, l4 = lane >> 4;
  const int lr = lane >> 2, lc = (lane & 3) * 8;
  f32x4 acc[4][4] = {};
  const u16* ga = A + (size_t)(m0 + w * 16 + lr) * K + lc;
  const u16* gb = Bt + (size_t)(n0 + w * 16 + lr) * K + lc;

  for (int kk = 0; kk < K; kk += 32) {
    __syncthreads();
    GLD16(ga + kk, &As[w * 16][0]);
    GLD16(ga + (size_t)64 * K + kk, &As[64 + w * 16][0]);
    GLD16(gb + kk, &Bs[w * 16][0]);
    GLD16(gb + (size_t)64 * K + kk, &Bs[64 + w * 16][0]);
    __syncthreads();
    bf16x8 af[4], bfr[4];
#pragma unroll
    for (int i = 0; i < 4; i++) {
      af[i] = *(const bf16x8*)&As[wm + i * 16 + l15][l4 * 8];
      bfr[i] = *(const bf16x8*)&Bs[wn + i * 16 + l15][l4 * 8];
    }
#pragma unroll
    for (int mi = 0; mi < 4; mi++)
#pragma unroll
      for (int ni = 0; ni < 4; ni++)
        acc[mi][ni] = mfma16(af[mi], bfr[ni], acc[mi][ni]);
  }
  // C frag: row=(l>>4)*4+r, col=l&15; scatter into [B,H,T,D]
#pragma unroll
  for (int mi = 0; mi < 4; mi++) {
#pragma unroll
    for (int ni = 0; ni < 4; ni++) {
#pragma unroll
      for (int r = 0; r < 4; r++) {
        int row = m0 + wm + mi * 16 + l4 * 4 + r;
        int col = n0 + wn + ni * 16 + l15;
        float val = acc[mi][ni][r] + bias[col];
        int which = col >> 10, c = col & 1023;
        int h = c >> 6, d = c & 63;
        int b = row >> 11, tt = row & 2047;
        u16* dst = (which == 0) ? qw : ((which == 1) ? kw : vw);
        dst[(size_t)((b * Hq + h) * Tq + tt) * Dq + d] = f2bf(val);
      }
    }
  }
}

// ---------------------------------------------------------------------------
// Kernel 2: causal flash attention v3.
// Block = 128 q-rows of one (b,h); 4 waves x 32 rows (2 strips of 16).
// KV tiles of 64. T14 async staging (load regs early, LDS-write late),
// XOR-swizzled Vt/Ps, balanced qb mapping, Q in registers.
// ---------------------------------------------------------------------------
__global__ __launch_bounds__(256) void attn(
    const u16* __restrict__ qw, const u16* __restrict__ kw,
    const u16* __restrict__ vw, u16* __restrict__ yw) {
  const int bh = blockIdx.x;                 // 32
  const int qy = blockIdx.y;                 // 16
  // pair heavy+light on each CU slot: {bid, bid+256} -> qb sums constant
  const int qb = (qy < 8) ? (15 - qy) : (qy - 8);
  __shared__ __align__(16) u16 Ks[64][72];   // [k][d] natural
  __shared__ __align__(16) u16 Vt[64][72];   // [d][k] granule-swizzled
  __shared__ __align__(16) u16 Ps[128][72];  // [q][k] granule-swizzled
  const int t = threadIdx.x, lane = t & 63, w = t >> 6;
  const int l15 = lane & 15, l4 = lane >> 4;
  const size_t base = (size_t)bh * Tq * Dq;
  const int rr = t >> 2, d0 = (t & 3) * 16;  // staging: row, col-start

  // Q -> registers: strips s, halves h
  bf16x8 qf[2][2];
  {
    const u16* qp = qw + base + (size_t)(qb * 128 + w * 32) * Dq;
#pragma unroll
    for (int s = 0; s < 2; s++)
#pragma unroll
      for (int h = 0; h < 2; h++)
        qf[s][h] = *(const bf16x8*)(qp + (size_t)(s * 16 + l15) * Dq + h * 32 + l4 * 8);
  }

  float m[2][4], lsum[2][4];
  f32x4 accO[2][4] = {};
#pragma unroll
  for (int s = 0; s < 2; s++)
#pragma unroll
    for (int r = 0; r < 4; r++) { m[s][r] = -1e30f; lsum[s][r] = 0.f; }

  const float kscale = 0.125f * 1.44269504088896340736f;  // exp2 domain
  const int kvmax = 2 * qb + 1;

  // prologue: issue kv=0 loads into regs
  const u16* ksrc = kw + base + (size_t)rr * Dq + d0;
  const u16* vsrc = vw + base + (size_t)rr * Dq + d0;
  uint4 kreg0 = *(const uint4*)ksrc, kreg1 = *(const uint4*)(ksrc + 8);
  uint4 vreg0 = *(const uint4*)vsrc, vreg1 = *(const uint4*)(vsrc + 8);

  for (int kv = 0; kv <= kvmax; kv++) {
    __syncthreads();  // all waves done reading previous tile
    // write staged regs -> LDS
    *(uint4*)&Ks[rr][d0] = kreg0;
    *(uint4*)&Ks[rr][d0 + 8] = kreg1;
    {
      union { uint4 q[2]; u16 s[16]; } vu;
      vu.q[0] = vreg0; vu.q[1] = vreg1;
#pragma unroll
      for (int j = 0; j < 16; j++) {
        int row = d0 + j;
        Vt[row][swz(rr, row)] = vu.s[j];
      }
    }
    // issue next tile's loads (in flight across the whole compute phase)
    if (kv < kvmax) {
      ksrc += 64 * Dq; vsrc += 64 * Dq;
      kreg0 = *(const uint4*)ksrc; kreg1 = *(const uint4*)(ksrc + 8);
      vreg0 = *(const uint4*)vsrc; vreg1 = *(const uint4*)(vsrc + 8);
    }
    __syncthreads();

    // QK^T: sc[strip][ct] covers [32 q][64 k]
    f32x4 sc[2][4];
    __builtin_amdgcn_s_setprio(1);
#pragma unroll
    for (int ct = 0; ct < 4; ct++) {
      bf16x8 kf0 = *(const bf16x8*)&Ks[ct * 16 + l15][l4 * 8];
      bf16x8 kf1 = *(const bf16x8*)&Ks[ct * 16 + l15][32 + l4 * 8];
      f32x4 z0 = {}; z0 = mfma16(qf[0][0], kf0, z0); z0 = mfma16(qf[0][1], kf1, z0);
      sc[0][ct] = z0;
      f32x4 z1 = {}; z1 = mfma16(qf[1][0], kf0, z1); z1 = mfma16(qf[1][1], kf1, z1);
      sc[1][ct] = z1;
    }
    __builtin_amdgcn_s_setprio(0);

    // scale (+ per-element causal mask only on the two diagonal tiles)
    if (kv >= 2 * qb) {
#pragma unroll
      for (int s = 0; s < 2; s++)
#pragma unroll
        for (int ct = 0; ct < 4; ct++)
#pragma unroll
          for (int r = 0; r < 4; r++) {
            int q = qb * 128 + w * 32 + s * 16 + l4 * 4 + r;
            int k = kv * 64 + ct * 16 + l15;
            sc[s][ct][r] = (k > q) ? -1e30f : sc[s][ct][r] * kscale;
          }
    } else {
#pragma unroll
      for (int s = 0; s < 2; s++)
#pragma unroll
        for (int ct = 0; ct < 4; ct++)
#pragma unroll
          for (int r = 0; r < 4; r++) sc[s][ct][r] *= kscale;
    }

    // online softmax per strip; P -> swizzled wave-private LDS
#pragma unroll
    for (int s = 0; s < 2; s++) {
      float corr[4], psum[4];
#pragma unroll
      for (int r = 0; r < 4; r++) {
        float v = fmaxf(fmaxf(sc[s][0][r], sc[s][1][r]),
                        fmaxf(sc[s][2][r], sc[s][3][r]));
#pragma unroll
        for (int off = 1; off < 16; off <<= 1) v = fmaxf(v, __shfl_xor(v, off));
        float mn = fmaxf(m[s][r], v);
        corr[r] = exp2f(m[s][r] - mn);
        m[s][r] = mn;
        psum[r] = 0.f;
      }
#pragma unroll
      for (int ct = 0; ct < 4; ct++)
#pragma unroll
        for (int r = 0; r < 4; r++) {
          float p = exp2f(sc[s][ct][r] - m[s][r]);
          psum[r] += p;
          int R = w * 32 + s * 16 + l4 * 4 + r;
          Ps[R][swz(ct * 16 + l15, R)] = f2bf(p);
        }
#pragma unroll
      for (int r = 0; r < 4; r++) {
        float v = psum[r];
#pragma unroll
        for (int off = 1; off < 16; off <<= 1) v += __shfl_xor(v, off);
        lsum[s][r] = lsum[s][r] * corr[r] + v;
      }
#pragma unroll
      for (int dt = 0; dt < 4; dt++)
#pragma unroll
        for (int r = 0; r < 4; r++) accO[s][dt][r] *= corr[r];
    }

    // PV: pf wave-private (in-wave LDS ordering), vf shared across strips
    bf16x8 pf[2][2];
#pragma unroll
    for (int s = 0; s < 2; s++) {
      int R = w * 32 + s * 16 + l15;
      int e = (R >> 3) & 7;
      pf[s][0] = *(const bf16x8*)&Ps[R][8 * ((l4 ^ e) & 7)];
      pf[s][1] = *(const bf16x8*)&Ps[R][8 * (((4 + l4) ^ e) & 7)];
    }
    __builtin_amdgcn_s_setprio(1);
#pragma unroll
    for (int dt = 0; dt < 4; dt++) {
      int Rv = dt * 16 + l15;
      int ev = (Rv >> 3) & 7;
      bf16x8 vf0 = *(const bf16x8*)&Vt[Rv][8 * ((l4 ^ ev) & 7)];
      bf16x8 vf1 = *(const bf16x8*)&Vt[Rv][8 * (((4 + l4) ^ ev) & 7)];
      accO[0][dt] = mfma16(pf[0][0], vf0, accO[0][dt]);
      accO[0][dt] = mfma16(pf[0][1], vf1, accO[0][dt]);
      accO[1][dt] = mfma16(pf[1][0], vf0, accO[1][dt]);
      accO[1][dt] = mfma16(pf[1][1], vf1, accO[1][dt]);
    }
    __builtin_amdgcn_s_setprio(0);
  }

  // epilogue: normalize, write y [B,T,C] bf16
  const int b = bh >> 4, hd = bh & 15;
#pragma unroll
  for (int s = 0; s < 2; s++)
#pragma unroll
    for (int r = 0; r < 4; r++) {
      float inv = 1.0f / lsum[s][r];
      int tt = qb * 128 + w * 32 + s * 16 + l4 * 4 + r;
      size_t rowbase = ((size_t)(b * Tq + tt)) * Cq + hd * 64;
#pragma unroll
      for (int dt = 0; dt < 4; dt++)
        yw[rowbase + dt * 16 + l15] = f2bf(accO[s][dt][r] * inv);
    }
}

// ---------------------------------------------------------------------------
// Kernel 3: out = y @ Wt_proj^T + b_proj (fp32 out). m97 structure.
// ---------------------------------------------------------------------------
__global__ __launch_bounds__(256) void proj_gemm(
    const u16* __restrict__ A, const u16* __restrict__ Bt,
    const float* __restrict__ bias, float* __restrict__ out) {
  const int K = 1024, N = 1024;
  __shared__ __align__(16) u16 As[128][32];
  __shared__ __align__(16) u16 Bs[128][32];
  const int m0 = blockIdx.x * 128, n0 = blockIdx.y * 128;
  const int t = threadIdx.x, lane = t & 63, w = t >> 6;
  const int wm = (w >> 1) * 64, wn = (w & 1) * 64;
  const int l15 = lane & 15, l4 = lane >> 4;
  const int lr = lane >> 2, lc = (lane & 3) * 8;
  f32x4 acc[4][4] = {};
  const u16* ga = A + (size_t)(m0 + w * 16 + lr) * K + lc;
  const u16* gb = Bt + (size_t)(n0 + w * 16 + lr) * K + lc;

  for (int kk = 0; kk < K; kk += 32) {
    __syncthreads();
    GLD16(ga + kk, &As[w * 16][0]);
    GLD16(ga + (size_t)64 * K + kk, &As[64 + w * 16][0]);
    GLD16(gb + kk, &Bs[w * 16][0]);
    GLD16(gb + (size_t)64 * K + kk, &Bs[64 + w * 16][0]);
    __syncthreads();
    bf16x8 af[4], bfr[4];
#pragma unroll
    for (int i = 0; i < 4; i++) {
      af[i] = *(const bf16x8*)&As[wm + i * 16 + l15][l4 * 8];
      bfr[i] = *(const bf16x8*)&Bs[wn + i * 16 + l15][l4 * 8];
    }
#pragma unroll
    for (int mi = 0; mi < 4; mi++)
#pragma unroll
      for (int ni = 0; ni < 4; ni++)
        acc[mi][ni] = mfma16(af[mi], bfr[ni], acc[mi][ni]);
  }
#pragma unroll
  for (int mi = 0; mi < 4; mi++) {
#pragma unroll
    for (int ni = 0; ni < 4; ni++) {
#pragma unroll
      for (int r = 0; r < 4; r++) {
        int row = m0 + wm + mi * 16 + l4 * 4 + r;
        int col = n0 + wn + ni * 16 + l15;
        out[(size_t)row * N + col] = acc[mi][ni][r] + bias[col];
      }
    }
  }
}

// ---------------------------------------------------------------------------
// Workspace (bytes): qw 8M | kw 8M | vw 8M | xb/yw 8M | Wt 6M = 38 MB
// ---------------------------------------------------------------------------
extern "C" void kernel_launch(void* const* d_in, const int* in_sizes, int n_in,
                              void* d_out, int out_size, void* d_ws, size_t ws_size,
                              hipStream_t stream) {
  const float* x = (const float*)d_in[0];
  const float* W_qkv = (const float*)d_in[1];
  const float* b_qkv = (const float*)d_in[2];
  const float* W_proj = (const float*)d_in[3];
  const float* b_proj = (const float*)d_in[4];
  float* out = (float*)d_out;

  const size_t qkv_elems = (size_t)Bq * Hq * Tq * Dq;  // 4M
  u16* qw = (u16*)d_ws;
  u16* kw = qw + qkv_elems;
  u16* vw = kw + qkv_elems;
  u16* xb = vw + qkv_elems;          // reused as yw after qkv_gemm
  u16* wt = xb + (size_t)Mq * Cq;    // 3072*1024 bf16 max

  convert_x<<<dim3((Mq * Cq) / (256 * 8)), 256, 0, stream>>>(x, xb);
  transpose_w<<<dim3(Cq / 64, 3 * Cq / 64), 256, 0, stream>>>(W_qkv, wt, Cq, 3 * Cq);
  qkv_gemm<<<dim3(Mq / 128, 3 * Cq / 128), 256, 0, stream>>>(xb, wt, b_qkv, qw, kw, vw);
  transpose_w<<<dim3(Cq / 64, Cq / 64), 256, 0, stream>>>(W_proj, wt, Cq, Cq);
  u16* yw = xb;
  attn<<<dim3(Bq * Hq, Tq / 128), 256, 0, stream>>>(qw, kw, vw, yw);
  proj_gemm<<<dim3(Mq / 128, Cq / 128), 256, 0, stream>>>(yw, wt, b_proj, out);
}

// Round 5
// 207.317 us; speedup vs baseline: 1.6812x; 1.2033x over previous
//
#include <hip/hip_runtime.h>
#include <hip/hip_bf16.h>

// Problem constants: B=2, T=2048, C=1024, H=16, D=64
#define Bq 2
#define Tq 2048
#define Cq 1024
#define Hq 16
#define Dq 64
#define Mq (Bq * Tq)  // 4096 rows

typedef __bf16 bf16x8 __attribute__((ext_vector_type(8)));
typedef float f32x4 __attribute__((ext_vector_type(4)));
typedef unsigned short u16;

static __device__ __forceinline__ u16 f2bf(float f) {
  union { float f; unsigned u; } v; v.f = f;
  return (u16)((v.u + 0x7fffu + ((v.u >> 16) & 1u)) >> 16);
}

static __device__ __forceinline__ f32x4 mfma16(bf16x8 a, bf16x8 b, f32x4 c) {
  return __builtin_amdgcn_mfma_f32_16x16x32_bf16(a, b, c, 0, 0, 0);
}

// async global->LDS, 16B per lane. LDS dest = wave-uniform base + lane*16.
#define GLD16(g, l)                                                   \
  __builtin_amdgcn_global_load_lds(                                   \
      (const __attribute__((address_space(1))) unsigned int*)(g),     \
      (__attribute__((address_space(3))) unsigned int*)(l), 16, 0, 0)

// XOR granule swizzle: 8-u16 granules, granule ^= (row>>3)&7.
static __device__ __forceinline__ int swz(int col, int row) {
  return (col & 7) + 8 * (((col >> 3) ^ (row >> 3)) & 7);
}

// ---------------------------------------------------------------------------
// Pre-pass A: x fp32 -> bf16 (4M elements)
// ---------------------------------------------------------------------------
__global__ __launch_bounds__(256) void convert_x(const float* __restrict__ x,
                                                 u16* __restrict__ xb) {
  int i = (blockIdx.x * 256 + threadIdx.x) * 8;
  float4 a = *(const float4*)(x + i);
  float4 b = *(const float4*)(x + i + 4);
  u16 tmp[8];
  tmp[0] = f2bf(a.x); tmp[1] = f2bf(a.y); tmp[2] = f2bf(a.z); tmp[3] = f2bf(a.w);
  tmp[4] = f2bf(b.x); tmp[5] = f2bf(b.y); tmp[6] = f2bf(b.z); tmp[7] = f2bf(b.w);
  *(uint4*)(xb + i) = *(const uint4*)tmp;
}

// ---------------------------------------------------------------------------
// Pre-pass B: W fp32 [K][N] -> Wt bf16 [N][K] (tiled transpose via LDS)
// ---------------------------------------------------------------------------
__global__ __launch_bounds__(256) void transpose_w(const float* __restrict__ W,
                                                   u16* __restrict__ Wt,
                                                   int K, int N) {
  __shared__ __align__(16) u16 Ts[64][72];  // [n][k]
  const int k0 = blockIdx.x * 64, n0 = blockIdx.y * 64;
  const int t = threadIdx.x;
  const int r = t >> 2, c0 = (t & 3) * 16;
  const float* src = W + (size_t)(k0 + r) * N + n0 + c0;
  u16 v16[16];
#pragma unroll
  for (int i = 0; i < 4; i++) {
    float4 f = *(const float4*)(src + 4 * i);
    v16[4 * i + 0] = f2bf(f.x); v16[4 * i + 1] = f2bf(f.y);
    v16[4 * i + 2] = f2bf(f.z); v16[4 * i + 3] = f2bf(f.w);
  }
#pragma unroll
  for (int j = 0; j < 16; j++) Ts[c0 + j][r] = v16[j];
  __syncthreads();
  u16* dst = Wt + (size_t)(n0 + r) * K + k0 + c0;
  *(uint4*)dst = *(const uint4*)&Ts[r][c0];
  *(uint4*)(dst + 8) = *(const uint4*)&Ts[r][c0 + 8];
}

// ---------------------------------------------------------------------------
// Kernel 1: QKV = xb @ Wt^T + b, scatter to Q/K/V [B,H,T,D] bf16.
// Q is pre-scaled by 0.125*log2(e) so attn works directly in exp2 domain.
// ---------------------------------------------------------------------------
__global__ __launch_bounds__(256) void qkv_gemm(
    const u16* __restrict__ A, const u16* __restrict__ Bt,
    const float* __restrict__ bias,
    u16* __restrict__ qw, u16* __restrict__ kw, u16* __restrict__ vw) {
  const int K = 1024;
  __shared__ __align__(16) u16 As[128][32];
  __shared__ __align__(16) u16 Bs[128][32];
  const int m0 = blockIdx.x * 128, n0 = blockIdx.y * 128;
  const int t = threadIdx.x, lane = t & 63, w = t >> 6;
  const int wm = (w >> 1) * 64, wn = (w & 1) * 64;
  const int l15 = lane & 15, l4 = lane >> 4;
  const int lr = lane >> 2, lc = (lane & 3) * 8;
  f32x4 acc[4][4] = {};
  const u16* ga = A + (size_t)(m0 + w * 16 + lr) * K + lc;
  const u16* gb = Bt + (size_t)(n0 + w * 16 + lr) * K + lc;

  for (int kk = 0; kk < K; kk += 32) {
    __syncthreads();
    GLD16(ga + kk, &As[w * 16][0]);
    GLD16(ga + (size_t)64 * K + kk, &As[64 + w * 16][0]);
    GLD16(gb + kk, &Bs[w * 16][0]);
    GLD16(gb + (size_t)64 * K + kk, &Bs[64 + w * 16][0]);
    __syncthreads();
    bf16x8 af[4], bfr[4];
#pragma unroll
    for (int i = 0; i < 4; i++) {
      af[i] = *(const bf16x8*)&As[wm + i * 16 + l15][l4 * 8];
      bfr[i] = *(const bf16x8*)&Bs[wn + i * 16 + l15][l4 * 8];
    }
#pragma unroll
    for (int mi = 0; mi < 4; mi++)
#pragma unroll
      for (int ni = 0; ni < 4; ni++)
        acc[mi][ni] = mfma16(af[mi], bfr[ni], acc[mi][ni]);
  }
  // C frag: row=(l>>4)*4+r, col=l&15; scatter into [B,H,T,D]
#pragma unroll
  for (int mi = 0; mi < 4; mi++) {
#pragma unroll
    for (int ni = 0; ni < 4; ni++) {
#pragma unroll
      for (int r = 0; r < 4; r++) {
        int row = m0 + wm + mi * 16 + l4 * 4 + r;
        int col = n0 + wn + ni * 16 + l15;
        float val = acc[mi][ni][r] + bias[col];
        int which = col >> 10, c = col & 1023;
        if (which == 0) val *= 0.18033688011112042f;  // 0.125 * log2(e)
        int h = c >> 6, d = c & 63;
        int b = row >> 11, tt = row & 2047;
        u16* dst = (which == 0) ? qw : ((which == 1) ? kw : vw);
        dst[(size_t)((b * Hq + h) * Tq + tt) * Dq + d] = f2bf(val);
      }
    }
  }
}

// ---------------------------------------------------------------------------
// Kernel 2: causal flash attention v4b — swapped QK^T, in-register P.
// 512 threads = 8 waves; block = 128 q-rows; wave w owns strip of 16 q.
// sc = mfma(K,Q): q = lane&15, k = ct*16 + (lane>>4)*4 + r.
// P redistribution FIX: destination-side ct select. Needed register is
// sc[2h + (dst_l4>>1)][r] from lane l15 + 32*(dst_l4&1) + 16*jh; a single
// source-side select cannot serve both halves -> shfl both, cndmask by l4>>1.
// ---------------------------------------------------------------------------
__global__ __launch_bounds__(512, 4) void attn(
    const u16* __restrict__ qw, const u16* __restrict__ kw,
    const u16* __restrict__ vw, u16* __restrict__ yw) {
  const int bh = blockIdx.x;                 // 32
  const int qy = blockIdx.y;                 // 16
  // pair heavy+light per CU slot: {bid, bid+256} -> constant work sum
  const int qb = (qy < 8) ? (15 - qy) : (qy - 8);
  __shared__ __align__(16) u16 Ks[64][72];   // [k][d] natural
  __shared__ __align__(16) u16 Vt[64][72];   // [d][k] granule-swizzled
  const int t = threadIdx.x, lane = t & 63, w = t >> 6;
  const int l15 = lane & 15, l4 = lane >> 4;
  const size_t base = (size_t)bh * Tq * Dq;
  const int rv = t >> 3, c8 = t & 7;         // staging: row, 16B chunk

  const int qs = qb * 128 + w * 16;          // strip base (global q)
  // Q fragments (B-operand): qf[h][j] = Qscaled[qs + l15][h*32 + l4*8 + j]
  bf16x8 qf[2];
  {
    const u16* qp = qw + base + (size_t)(qs + l15) * Dq + l4 * 8;
    qf[0] = *(const bf16x8*)qp;
    qf[1] = *(const bf16x8*)(qp + 32);
  }

  float m = -1e30f, lsum = 0.f;
  f32x4 accO[4] = {};
  const int kvmax = 2 * qb + 1;

  // T14: prologue loads for kv=0
  const u16* ksrc = kw + base + (size_t)rv * Dq + c8 * 8;
  const u16* vsrc = vw + base + (size_t)rv * Dq + c8 * 8;
  uint4 kreg = *(const uint4*)ksrc;
  uint4 vreg = *(const uint4*)vsrc;

  for (int kv = 0; kv <= kvmax; kv++) {
    __syncthreads();  // all waves done reading previous tile
    *(uint4*)&Ks[rv][c8 * 8] = kreg;
    {
      union { uint4 q; u16 s[8]; } vu; vu.q = vreg;
#pragma unroll
      for (int jj = 0; jj < 8; jj++) {
        int row = c8 * 8 + jj;
        Vt[row][swz(rv, row)] = vu.s[jj];
      }
    }
    if (kv < kvmax) {  // issue next tile's loads (in flight across compute)
      ksrc += 64 * Dq; vsrc += 64 * Dq;
      kreg = *(const uint4*)ksrc;
      vreg = *(const uint4*)vsrc;
    }
    __syncthreads();

    if (kv * 64 > qs + 15) continue;  // tile fully masked for this strip

    // swapped QK^T: sc[ct][r] = S[k = kv*64 + ct*16 + l4*4 + r][q = qs+l15]
    f32x4 sc[4];
    __builtin_amdgcn_s_setprio(1);
#pragma unroll
    for (int ct = 0; ct < 4; ct++) {
      bf16x8 kf0 = *(const bf16x8*)&Ks[ct * 16 + l15][l4 * 8];
      bf16x8 kf1 = *(const bf16x8*)&Ks[ct * 16 + l15][32 + l4 * 8];
      f32x4 z = {};
      z = mfma16(kf0, qf[0], z);
      z = mfma16(kf1, qf[1], z);
      sc[ct] = z;
    }
    __builtin_amdgcn_s_setprio(0);

    if (kv * 64 + 63 > qs) {  // diagonal region: causal mask
      const int q = qs + l15;
#pragma unroll
      for (int ct = 0; ct < 4; ct++)
#pragma unroll
        for (int r = 0; r < 4; r++) {
          int k = kv * 64 + ct * 16 + l4 * 4 + r;
          if (k > q) sc[ct][r] = -1e30f;
        }
    }

    // row max: 15 lane-local fmax + 2 shfl (group {l15, +16, +32, +48})
    float pmax = sc[0][0];
#pragma unroll
    for (int ct = 0; ct < 4; ct++)
#pragma unroll
      for (int r = 0; r < 4; r++) pmax = fmaxf(pmax, sc[ct][r]);
    pmax = fmaxf(pmax, __shfl_xor(pmax, 16));
    pmax = fmaxf(pmax, __shfl_xor(pmax, 32));

    // defer-max (T13): only rescale when max grew past threshold
    if (__any(pmax > m + 8.f)) {
      float mn = fmaxf(m, pmax);
      float corr = exp2f(m - mn);
      m = mn;
      lsum *= corr;
#pragma unroll
      for (int r = 0; r < 4; r++) {  // corr for q=l4*4+r lives at lane 20*l4+r
        float cb = __shfl(corr, (lane >> 4) * 20 + r);
#pragma unroll
        for (int dt = 0; dt < 4; dt++) accO[dt][r] *= cb;
      }
    }

    // P = exp2(sc - m), in place; lane-local psum + 2 shfl
    float psum = 0.f;
#pragma unroll
    for (int ct = 0; ct < 4; ct++)
#pragma unroll
      for (int r = 0; r < 4; r++) {
        float p = exp2f(sc[ct][r] - m);
        sc[ct][r] = p;
        psum += p;
      }
    psum += __shfl_xor(psum, 16);
    psum += __shfl_xor(psum, 32);
    lsum += psum;

    // redistribute P into PV A-operand (DEST-side select):
    // pa[h][jh*4+r] = sc'[2h + (l4>>1)][r] read from lane
    //                 l15 + 32*(l4&1) + 16*jh
    bf16x8 pa[2];
    const int bsrc = ((lane & 16) << 1) + l15;  // 32*(l4&1) + l15
#pragma unroll
    for (int h = 0; h < 2; h++) {
#pragma unroll
      for (int jh = 0; jh < 2; jh++)
#pragma unroll
        for (int r = 0; r < 4; r++) {
          float v0 = __shfl(sc[2 * h][r], bsrc + 16 * jh);
          float v1 = __shfl(sc[2 * h + 1][r], bsrc + 16 * jh);
          pa[h][jh * 4 + r] = (__bf16)((l4 & 2) ? v1 : v0);
        }
    }

    // PV: accO[dt] += pa[h] x Vt-frags (b128 swizzled reads)
    __builtin_amdgcn_s_setprio(1);
#pragma unroll
    for (int dt = 0; dt < 4; dt++) {
      int Rv = dt * 16 + l15;
      int e = (Rv >> 3) & 7;
      bf16x8 vf0 = *(const bf16x8*)&Vt[Rv][8 * ((l4 ^ e) & 7)];
      bf16x8 vf1 = *(const bf16x8*)&Vt[Rv][8 * (((4 + l4) ^ e) & 7)];
      accO[dt] = mfma16(pa[0], vf0, accO[dt]);
      accO[dt] = mfma16(pa[1], vf1, accO[dt]);
    }
    __builtin_amdgcn_s_setprio(0);
  }

  // epilogue: O rows live at q = l4*4+r; inv for that q lives at lane 20*l4+r
  float inv = 1.0f / lsum;
  const int b = bh >> 4, hd = bh & 15;
#pragma unroll
  for (int r = 0; r < 4; r++) {
    float ib = __shfl(inv, (lane >> 4) * 20 + r);
    int tt = qs + l4 * 4 + r;
    size_t rowbase = ((size_t)(b * Tq + tt)) * Cq + hd * 64;
#pragma unroll
    for (int dt = 0; dt < 4; dt++)
      yw[rowbase + dt * 16 + l15] = f2bf(accO[dt][r] * ib);
  }
}

// ---------------------------------------------------------------------------
// Kernel 3: out = y @ Wt_proj^T + b_proj (fp32 out). m97 structure.
// ---------------------------------------------------------------------------
__global__ __launch_bounds__(256) void proj_gemm(
    const u16* __restrict__ A, const u16* __restrict__ Bt,
    const float* __restrict__ bias, float* __restrict__ out) {
  const int K = 1024, N = 1024;
  __shared__ __align__(16) u16 As[128][32];
  __shared__ __align__(16) u16 Bs[128][32];
  const int m0 = blockIdx.x * 128, n0 = blockIdx.y * 128;
  const int t = threadIdx.x, lane = t & 63, w = t >> 6;
  const int wm = (w >> 1) * 64, wn = (w & 1) * 64;
  const int l15 = lane & 15, l4 = lane >> 4;
  const int lr = lane >> 2, lc = (lane & 3) * 8;
  f32x4 acc[4][4] = {};
  const u16* ga = A + (size_t)(m0 + w * 16 + lr) * K + lc;
  const u16* gb = Bt + (size_t)(n0 + w * 16 + lr) * K + lc;

  for (int kk = 0; kk < K; kk += 32) {
    __syncthreads();
    GLD16(ga + kk, &As[w * 16][0]);
    GLD16(ga + (size_t)64 * K + kk, &As[64 + w * 16][0]);
    GLD16(gb + kk, &Bs[w * 16][0]);
    GLD16(gb + (size_t)64 * K + kk, &Bs[64 + w * 16][0]);
    __syncthreads();
    bf16x8 af[4], bfr[4];
#pragma unroll
    for (int i = 0; i < 4; i++) {
      af[i] = *(const bf16x8*)&As[wm + i * 16 + l15][l4 * 8];
      bfr[i] = *(const bf16x8*)&Bs[wn + i * 16 + l15][l4 * 8];
    }
#pragma unroll
    for (int mi = 0; mi < 4; mi++)
#pragma unroll
      for (int ni = 0; ni < 4; ni++)
        acc[mi][ni] = mfma16(af[mi], bfr[ni], acc[mi][ni]);
  }
#pragma unroll
  for (int mi = 0; mi < 4; mi++) {
#pragma unroll
    for (int ni = 0; ni < 4; ni++) {
#pragma unroll
      for (int r = 0; r < 4; r++) {
        int row = m0 + wm + mi * 16 + l4 * 4 + r;
        int col = n0 + wn + ni * 16 + l15;
        out[(size_t)row * N + col] = acc[mi][ni][r] + bias[col];
      }
    }
  }
}

// ---------------------------------------------------------------------------
// Workspace (bytes): qw 8M | kw 8M | vw 8M | xb/yw 8M | Wt 6M = 38 MB
// ---------------------------------------------------------------------------
extern "C" void kernel_launch(void* const* d_in, const int* in_sizes, int n_in,
                              void* d_out, int out_size, void* d_ws, size_t ws_size,
                              hipStream_t stream) {
  const float* x = (const float*)d_in[0];
  const float* W_qkv = (const float*)d_in[1];
  const float* b_qkv = (const float*)d_in[2];
  const float* W_proj = (const float*)d_in[3];
  const float* b_proj = (const float*)d_in[4];
  float* out = (float*)d_out;

  const size_t qkv_elems = (size_t)Bq * Hq * Tq * Dq;  // 4M
  u16* qw = (u16*)d_ws;
  u16* kw = qw + qkv_elems;
  u16* vw = kw + qkv_elems;
  u16* xb = vw + qkv_elems;          // reused as yw after qkv_gemm
  u16* wt = xb + (size_t)Mq * Cq;    // 3072*1024 bf16 max

  convert_x<<<dim3((Mq * Cq) / (256 * 8)), 256, 0, stream>>>(x, xb);
  transpose_w<<<dim3(Cq / 64, 3 * Cq / 64), 256, 0, stream>>>(W_qkv, wt, Cq, 3 * Cq);
  qkv_gemm<<<dim3(Mq / 128, 3 * Cq / 128), 256, 0, stream>>>(xb, wt, b_qkv, qw, kw, vw);
  transpose_w<<<dim3(Cq / 64, Cq / 64), 256, 0, stream>>>(W_proj, wt, Cq, Cq);
  u16* yw = xb;
  attn<<<dim3(Bq * Hq, Tq / 128), 512, 0, stream>>>(qw, kw, vw, yw);
  proj_gemm<<<dim3(Mq / 128, Cq / 128), 256, 0, stream>>>(yw, wt, b_proj, out);
}

// Round 6
// 203.668 us; speedup vs baseline: 1.7114x; 1.0179x over previous
//
#include <hip/hip_runtime.h>
#include <hip/hip_bf16.h>

// Problem constants: B=2, T=2048, C=1024, H=16, D=64
#define Bq 2
#define Tq 2048
#define Cq 1024
#define Hq 16
#define Dq 64
#define Mq (Bq * Tq)  // 4096 rows

typedef __bf16 bf16x8 __attribute__((ext_vector_type(8)));
typedef float f32x4 __attribute__((ext_vector_type(4)));
typedef unsigned uint4v __attribute__((ext_vector_type(4)));
typedef unsigned short u16;

static __device__ __forceinline__ u16 f2bf(float f) {
  union { float f; unsigned u; } v; v.f = f;
  return (u16)((v.u + 0x7fffu + ((v.u >> 16) & 1u)) >> 16);
}

static __device__ __forceinline__ unsigned cvt_pk_bf16(float a, float b) {
  unsigned r;
  asm("v_cvt_pk_bf16_f32 %0, %1, %2" : "=v"(r) : "v"(a), "v"(b));
  return r;  // lo = bf16(a), hi = bf16(b), RNE
}

static __device__ __forceinline__ f32x4 mfma16(bf16x8 a, bf16x8 b, f32x4 c) {
  return __builtin_amdgcn_mfma_f32_16x16x32_bf16(a, b, c, 0, 0, 0);
}

// async global->LDS, 16B per lane. LDS dest = wave-uniform base + lane*16.
#define GLD16(g, l)                                                   \
  __builtin_amdgcn_global_load_lds(                                   \
      (const __attribute__((address_space(1))) unsigned int*)(g),     \
      (__attribute__((address_space(3))) unsigned int*)(l), 16, 0, 0)

// XOR granule swizzle: 8-u16 granules, granule ^= (row>>3)&7.
static __device__ __forceinline__ int swz(int col, int row) {
  return (col & 7) + 8 * (((col >> 3) ^ (row >> 3)) & 7);
}

// ---------------------------------------------------------------------------
// Pre-pass A: x fp32 -> bf16 (4M elements)
// ---------------------------------------------------------------------------
__global__ __launch_bounds__(256) void convert_x(const float* __restrict__ x,
                                                 u16* __restrict__ xb) {
  int i = (blockIdx.x * 256 + threadIdx.x) * 8;
  float4 a = *(const float4*)(x + i);
  float4 b = *(const float4*)(x + i + 4);
  u16 tmp[8];
  tmp[0] = f2bf(a.x); tmp[1] = f2bf(a.y); tmp[2] = f2bf(a.z); tmp[3] = f2bf(a.w);
  tmp[4] = f2bf(b.x); tmp[5] = f2bf(b.y); tmp[6] = f2bf(b.z); tmp[7] = f2bf(b.w);
  *(uint4*)(xb + i) = *(const uint4*)tmp;
}

// ---------------------------------------------------------------------------
// Pre-pass B: W fp32 [K][N] -> Wt bf16 [N][K] (tiled transpose via LDS)
// ---------------------------------------------------------------------------
__global__ __launch_bounds__(256) void transpose_w(const float* __restrict__ W,
                                                   u16* __restrict__ Wt,
                                                   int K, int N) {
  __shared__ __align__(16) u16 Ts[64][72];  // [n][k]
  const int k0 = blockIdx.x * 64, n0 = blockIdx.y * 64;
  const int t = threadIdx.x;
  const int r = t >> 2, c0 = (t & 3) * 16;
  const float* src = W + (size_t)(k0 + r) * N + n0 + c0;
  u16 v16[16];
#pragma unroll
  for (int i = 0; i < 4; i++) {
    float4 f = *(const float4*)(src + 4 * i);
    v16[4 * i + 0] = f2bf(f.x); v16[4 * i + 1] = f2bf(f.y);
    v16[4 * i + 2] = f2bf(f.z); v16[4 * i + 3] = f2bf(f.w);
  }
#pragma unroll
  for (int j = 0; j < 16; j++) Ts[c0 + j][r] = v16[j];
  __syncthreads();
  u16* dst = Wt + (size_t)(n0 + r) * K + k0 + c0;
  *(uint4*)dst = *(const uint4*)&Ts[r][c0];
  *(uint4*)(dst + 8) = *(const uint4*)&Ts[r][c0 + 8];
}

// ---------------------------------------------------------------------------
// Kernel 1: QKV = xb @ Wt^T + b, scatter to Q/K/V [B,H,T,D] bf16.
// Q is pre-scaled by 0.125*log2(e) so attn works directly in exp2 domain.
// ---------------------------------------------------------------------------
__global__ __launch_bounds__(256) void qkv_gemm(
    const u16* __restrict__ A, const u16* __restrict__ Bt,
    const float* __restrict__ bias,
    u16* __restrict__ qw, u16* __restrict__ kw, u16* __restrict__ vw) {
  const int K = 1024;
  __shared__ __align__(16) u16 As[128][32];
  __shared__ __align__(16) u16 Bs[128][32];
  const int m0 = blockIdx.x * 128, n0 = blockIdx.y * 128;
  const int t = threadIdx.x, lane = t & 63, w = t >> 6;
  const int wm = (w >> 1) * 64, wn = (w & 1) * 64;
  const int l15 = lane & 15, l4 = lane >> 4;
  const int lr = lane >> 2, lc = (lane & 3) * 8;
  f32x4 acc[4][4] = {};
  const u16* ga = A + (size_t)(m0 + w * 16 + lr) * K + lc;
  const u16* gb = Bt + (size_t)(n0 + w * 16 + lr) * K + lc;

  for (int kk = 0; kk < K; kk += 32) {
    __syncthreads();
    GLD16(ga + kk, &As[w * 16][0]);
    GLD16(ga + (size_t)64 * K + kk, &As[64 + w * 16][0]);
    GLD16(gb + kk, &Bs[w * 16][0]);
    GLD16(gb + (size_t)64 * K + kk, &Bs[64 + w * 16][0]);
    __syncthreads();
    bf16x8 af[4], bfr[4];
#pragma unroll
    for (int i = 0; i < 4; i++) {
      af[i] = *(const bf16x8*)&As[wm + i * 16 + l15][l4 * 8];
      bfr[i] = *(const bf16x8*)&Bs[wn + i * 16 + l15][l4 * 8];
    }
#pragma unroll
    for (int mi = 0; mi < 4; mi++)
#pragma unroll
      for (int ni = 0; ni < 4; ni++)
        acc[mi][ni] = mfma16(af[mi], bfr[ni], acc[mi][ni]);
  }
  // C frag: row=(l>>4)*4+r, col=l&15; scatter into [B,H,T,D]
#pragma unroll
  for (int mi = 0; mi < 4; mi++) {
#pragma unroll
    for (int ni = 0; ni < 4; ni++) {
#pragma unroll
      for (int r = 0; r < 4; r++) {
        int row = m0 + wm + mi * 16 + l4 * 4 + r;
        int col = n0 + wn + ni * 16 + l15;
        float val = acc[mi][ni][r] + bias[col];
        int which = col >> 10, c = col & 1023;
        if (which == 0) val *= 0.18033688011112042f;  // 0.125 * log2(e)
        int h = c >> 6, d = c & 63;
        int b = row >> 11, tt = row & 2047;
        u16* dst = (which == 0) ? qw : ((which == 1) ? kw : vw);
        dst[(size_t)((b * Hq + h) * Tq + tt) * Dq + d] = f2bf(val);
      }
    }
  }
}

// ---------------------------------------------------------------------------
// Kernel 2: causal flash attention v5 — 4 waves x 2 strips, packed shuffles.
// 256 threads; block = 128 q-rows; wave w owns strips qs0 = qb*128+w*32 (+16).
// Since strip bases are ==0 (mod 32), both strips share the tile-skip
// condition. K/V frag reads (16 x b128/tile) shared across both strips.
// P redistribution: pack S->bf16 pairs (cvt_pk) THEN shuffle u32s: 16
// bpermutes per strip-tile (was 32), dest-side select by l4&2 (v4b-verified).
// ---------------------------------------------------------------------------
__global__ __launch_bounds__(256, 3) void attn(
    const u16* __restrict__ qw, const u16* __restrict__ kw,
    const u16* __restrict__ vw, u16* __restrict__ yw) {
  const int bh = blockIdx.x;                 // 32
  const int qy = blockIdx.y;                 // 16
  // pair heavy+light per CU slot: {bid, bid+256} -> constant work sum
  const int qb = (qy < 8) ? (15 - qy) : (qy - 8);
  __shared__ __align__(16) u16 Ks[64][72];   // [k][d] natural
  __shared__ __align__(16) u16 Vt[64][72];   // [d][k] granule-swizzled
  const int t = threadIdx.x, lane = t & 63, w = t >> 6;  // w in 0..3
  const int l15 = lane & 15, l4 = lane >> 4;
  const size_t base = (size_t)bh * Tq * Dq;
  const int rv = t >> 2, d0 = (t & 3) * 16;  // staging: row, 16-u16 chunk

  const int qs0 = qb * 128 + w * 32;         // strip-0 base (strip1 = +16)
  // Q fragments (B-operand) per strip: qf[s][h]
  bf16x8 qf[2][2];
  {
    const u16* qp = qw + base + (size_t)(qs0 + l15) * Dq + l4 * 8;
    qf[0][0] = *(const bf16x8*)qp;
    qf[0][1] = *(const bf16x8*)(qp + 32);
    qf[1][0] = *(const bf16x8*)(qp + 16 * Dq);
    qf[1][1] = *(const bf16x8*)(qp + 16 * Dq + 32);
  }

  float m[2] = {-1e30f, -1e30f}, lsum[2] = {0.f, 0.f};
  f32x4 accO[2][4] = {};
  const int kvmax = 2 * qb + 1;

  // T14: prologue loads for kv=0 (2 uint4 per matrix per thread)
  const u16* ksrc = kw + base + (size_t)rv * Dq + d0;
  const u16* vsrc = vw + base + (size_t)rv * Dq + d0;
  uint4 kreg0 = *(const uint4*)ksrc, kreg1 = *(const uint4*)(ksrc + 8);
  uint4 vreg0 = *(const uint4*)vsrc, vreg1 = *(const uint4*)(vsrc + 8);

  for (int kv = 0; kv <= kvmax; kv++) {
    __syncthreads();  // all waves done reading previous tile
    *(uint4*)&Ks[rv][d0] = kreg0;
    *(uint4*)&Ks[rv][d0 + 8] = kreg1;
    {
      union { uint4 q[2]; u16 s[16]; } vu;
      vu.q[0] = vreg0; vu.q[1] = vreg1;
#pragma unroll
      for (int jj = 0; jj < 16; jj++) {
        int row = d0 + jj;
        Vt[row][swz(rv, row)] = vu.s[jj];
      }
    }
    if (kv < kvmax) {  // issue next tile's loads (in flight across compute)
      ksrc += 64 * Dq; vsrc += 64 * Dq;
      kreg0 = *(const uint4*)ksrc; kreg1 = *(const uint4*)(ksrc + 8);
      vreg0 = *(const uint4*)vsrc; vreg1 = *(const uint4*)(vsrc + 8);
    }
    __syncthreads();

    if (kv * 64 > qs0 + 31) continue;  // both strips masked

    // swapped QK^T for both strips; K frags read once
    f32x4 sc[2][4];
    __builtin_amdgcn_s_setprio(1);
#pragma unroll
    for (int ct = 0; ct < 4; ct++) {
      bf16x8 kf0 = *(const bf16x8*)&Ks[ct * 16 + l15][l4 * 8];
      bf16x8 kf1 = *(const bf16x8*)&Ks[ct * 16 + l15][32 + l4 * 8];
      f32x4 z0 = {};
      z0 = mfma16(kf0, qf[0][0], z0); z0 = mfma16(kf1, qf[0][1], z0);
      sc[0][ct] = z0;
      f32x4 z1 = {};
      z1 = mfma16(kf0, qf[1][0], z1); z1 = mfma16(kf1, qf[1][1], z1);
      sc[1][ct] = z1;
    }
    __builtin_amdgcn_s_setprio(0);

    if (kv * 64 + 63 > qs0) {  // diagonal region: per-element causal mask
#pragma unroll
      for (int s = 0; s < 2; s++) {
        const int q = qs0 + s * 16 + l15;
#pragma unroll
        for (int ct = 0; ct < 4; ct++)
#pragma unroll
          for (int r = 0; r < 4; r++) {
            int k = kv * 64 + ct * 16 + l4 * 4 + r;
            if (k > q) sc[s][ct][r] = -1e30f;
          }
      }
    }

    // per-strip online softmax + pack + redistribute
    bf16x8 pa[2][2];
    const int bsrc = ((lane & 16) << 1) + l15;  // 32*(l4&1) + l15
#pragma unroll
    for (int s = 0; s < 2; s++) {
      float pmax = sc[s][0][0];
#pragma unroll
      for (int ct = 0; ct < 4; ct++)
#pragma unroll
        for (int r = 0; r < 4; r++) pmax = fmaxf(pmax, sc[s][ct][r]);
      pmax = fmaxf(pmax, __shfl_xor(pmax, 16));
      pmax = fmaxf(pmax, __shfl_xor(pmax, 32));

      if (__any(pmax > m[s] + 8.f)) {  // defer-max (T13)
        float mn = fmaxf(m[s], pmax);
        float corr = exp2f(m[s] - mn);
        m[s] = mn;
        lsum[s] *= corr;
#pragma unroll
        for (int r = 0; r < 4; r++) {  // corr for q=l4*4+r at lane 20*l4+r
          float cb = __shfl(corr, (lane >> 4) * 20 + r);
#pragma unroll
          for (int dt = 0; dt < 4; dt++) accO[s][dt][r] *= cb;
        }
      }

      float psum = 0.f;
#pragma unroll
      for (int ct = 0; ct < 4; ct++)
#pragma unroll
        for (int r = 0; r < 4; r++) {
          float p = exp2f(sc[s][ct][r] - m[s]);
          sc[s][ct][r] = p;
          psum += p;
        }
      psum += __shfl_xor(psum, 16);
      psum += __shfl_xor(psum, 32);
      lsum[s] += psum;

      // pack P to bf16 pairs, then shuffle u32s (16 bpermutes)
      unsigned pk[4][2];
#pragma unroll
      for (int ct = 0; ct < 4; ct++)
#pragma unroll
        for (int hw = 0; hw < 2; hw++)
          pk[ct][hw] = cvt_pk_bf16(sc[s][ct][2 * hw], sc[s][ct][2 * hw + 1]);
#pragma unroll
      for (int h = 0; h < 2; h++) {
        uint4v pu;
#pragma unroll
        for (int jh = 0; jh < 2; jh++)
#pragma unroll
          for (int hw = 0; hw < 2; hw++) {
            unsigned w0 = __shfl(pk[2 * h][hw], bsrc + 16 * jh);
            unsigned w1 = __shfl(pk[2 * h + 1][hw], bsrc + 16 * jh);
            pu[jh * 2 + hw] = (l4 & 2) ? w1 : w0;
          }
        pa[s][h] = __builtin_bit_cast(bf16x8, pu);
      }
    }

    // PV: V frags read once, used by both strips
    __builtin_amdgcn_s_setprio(1);
#pragma unroll
    for (int dt = 0; dt < 4; dt++) {
      int Rv = dt * 16 + l15;
      int e = (Rv >> 3) & 7;
      bf16x8 vf0 = *(const bf16x8*)&Vt[Rv][8 * ((l4 ^ e) & 7)];
      bf16x8 vf1 = *(const bf16x8*)&Vt[Rv][8 * (((4 + l4) ^ e) & 7)];
      accO[0][dt] = mfma16(pa[0][0], vf0, accO[0][dt]);
      accO[0][dt] = mfma16(pa[0][1], vf1, accO[0][dt]);
      accO[1][dt] = mfma16(pa[1][0], vf0, accO[1][dt]);
      accO[1][dt] = mfma16(pa[1][1], vf1, accO[1][dt]);
    }
    __builtin_amdgcn_s_setprio(0);
  }

  // epilogue: O rows q = l4*4+r; inv for that q lives at lane 20*l4+r
  const int b = bh >> 4, hd = bh & 15;
#pragma unroll
  for (int s = 0; s < 2; s++) {
    float inv = 1.0f / lsum[s];
#pragma unroll
    for (int r = 0; r < 4; r++) {
      float ib = __shfl(inv, (lane >> 4) * 20 + r);
      int tt = qs0 + s * 16 + l4 * 4 + r;
      size_t rowbase = ((size_t)(b * Tq + tt)) * Cq + hd * 64;
#pragma unroll
      for (int dt = 0; dt < 4; dt++)
        yw[rowbase + dt * 16 + l15] = f2bf(accO[s][dt][r] * ib);
    }
  }
}

// ---------------------------------------------------------------------------
// Kernel 3: out = y @ Wt_proj^T + b_proj (fp32 out). m97 structure.
// ---------------------------------------------------------------------------
__global__ __launch_bounds__(256) void proj_gemm(
    const u16* __restrict__ A, const u16* __restrict__ Bt,
    const float* __restrict__ bias, float* __restrict__ out) {
  const int K = 1024, N = 1024;
  __shared__ __align__(16) u16 As[128][32];
  __shared__ __align__(16) u16 Bs[128][32];
  const int m0 = blockIdx.x * 128, n0 = blockIdx.y * 128;
  const int t = threadIdx.x, lane = t & 63, w = t >> 6;
  const int wm = (w >> 1) * 64, wn = (w & 1) * 64;
  const int l15 = lane & 15, l4 = lane >> 4;
  const int lr = lane >> 2, lc = (lane & 3) * 8;
  f32x4 acc[4][4] = {};
  const u16* ga = A + (size_t)(m0 + w * 16 + lr) * K + lc;
  const u16* gb = Bt + (size_t)(n0 + w * 16 + lr) * K + lc;

  for (int kk = 0; kk < K; kk += 32) {
    __syncthreads();
    GLD16(ga + kk, &As[w * 16][0]);
    GLD16(ga + (size_t)64 * K + kk, &As[64 + w * 16][0]);
    GLD16(gb + kk, &Bs[w * 16][0]);
    GLD16(gb + (size_t)64 * K + kk, &Bs[64 + w * 16][0]);
    __syncthreads();
    bf16x8 af[4], bfr[4];
#pragma unroll
    for (int i = 0; i < 4; i++) {
      af[i] = *(const bf16x8*)&As[wm + i * 16 + l15][l4 * 8];
      bfr[i] = *(const bf16x8*)&Bs[wn + i * 16 + l15][l4 * 8];
    }
#pragma unroll
    for (int mi = 0; mi < 4; mi++)
#pragma unroll
      for (int ni = 0; ni < 4; ni++)
        acc[mi][ni] = mfma16(af[mi], bfr[ni], acc[mi][ni]);
  }
#pragma unroll
  for (int mi = 0; mi < 4; mi++) {
#pragma unroll
    for (int ni = 0; ni < 4; ni++) {
#pragma unroll
      for (int r = 0; r < 4; r++) {
        int row = m0 + wm + mi * 16 + l4 * 4 + r;
        int col = n0 + wn + ni * 16 + l15;
        out[(size_t)row * N + col] = acc[mi][ni][r] + bias[col];
      }
    }
  }
}

// ---------------------------------------------------------------------------
// Workspace (bytes): qw 8M | kw 8M | vw 8M | xb/yw 8M | Wt 6M = 38 MB
// ---------------------------------------------------------------------------
extern "C" void kernel_launch(void* const* d_in, const int* in_sizes, int n_in,
                              void* d_out, int out_size, void* d_ws, size_t ws_size,
                              hipStream_t stream) {
  const float* x = (const float*)d_in[0];
  const float* W_qkv = (const float*)d_in[1];
  const float* b_qkv = (const float*)d_in[2];
  const float* W_proj = (const float*)d_in[3];
  const float* b_proj = (const float*)d_in[4];
  float* out = (float*)d_out;

  const size_t qkv_elems = (size_t)Bq * Hq * Tq * Dq;  // 4M
  u16* qw = (u16*)d_ws;
  u16* kw = qw + qkv_elems;
  u16* vw = kw + qkv_elems;
  u16* xb = vw + qkv_elems;          // reused as yw after qkv_gemm
  u16* wt = xb + (size_t)Mq * Cq;    // 3072*1024 bf16 max

  convert_x<<<dim3((Mq * Cq) / (256 * 8)), 256, 0, stream>>>(x, xb);
  transpose_w<<<dim3(Cq / 64, 3 * Cq / 64), 256, 0, stream>>>(W_qkv, wt, Cq, 3 * Cq);
  qkv_gemm<<<dim3(Mq / 128, 3 * Cq / 128), 256, 0, stream>>>(xb, wt, b_qkv, qw, kw, vw);
  transpose_w<<<dim3(Cq / 64, Cq / 64), 256, 0, stream>>>(W_proj, wt, Cq, Cq);
  u16* yw = xb;
  attn<<<dim3(Bq * Hq, Tq / 128), 256, 0, stream>>>(qw, kw, vw, yw);
  proj_gemm<<<dim3(Mq / 128, Cq / 128), 256, 0, stream>>>(yw, wt, b_proj, out);
}